// Round 11
// baseline (559.680 us; speedup 1.0000x reference)
//
#include <hip/hip_runtime.h>
#include <stdint.h>

// B=4, DIM=192, H=W=64, N=4096, HEADS=8, HD=24, SR=4, PLEN=256, LL=9
// All inputs f32, output f32.

__device__ __forceinline__ float b2f(unsigned short u) {
  return __uint_as_float(((unsigned)u) << 16);
}
__device__ __forceinline__ unsigned short f2b(float f) {
  unsigned x = __float_as_uint(f);
  return (unsigned short)((x + 0x7fffu + ((x >> 16) & 1u)) >> 16);
}

// ---------------- workspace layout (floats) ----------------
constexpr size_t OFF_T    = 0;          // (B,N,192)
constexpr size_t OFF_KMAP = 3145728;    // (B,384,N); early: conv partials 1+2
constexpr size_t OFF_QN   = 9437184;    // (B,8,24,N)
constexpr size_t OFF_QS   = 12582912;   // (B,8,24,N)
constexpr size_t OFF_CTX  = 15728640;   // (B,8,24,N)  (early: scratch for W transposes)
constexpr size_t OFF_POOL = 18874368;   // (B,256,192)
constexpr size_t OFF_KP   = 19070976;   // (B,8,256,24)
constexpr size_t OFF_VP   = 19267584;   // (B,8,256,24)
constexpr size_t OFF_CPB  = 19464192;   // (T,8)
constexpr size_t OFF_BIAS = 19595264;   // bf16 (8,4096,256) = 16.7 M ushort  [h][n][m]
constexpr size_t OFF_WTC  = OFF_CTX;              // conv wt [1728][192]
constexpr size_t OFF_QT   = OFF_CTX + 331776;     // [192][192]
constexpr size_t OFF_KVT  = OFF_CTX + 368640;     // [192][384]
constexpr size_t OFF_SRT  = OFF_CTX + 442368;     // [192][192]
constexpr size_t OFF_PJT  = OFF_KMAP;             // [192][192], created AFTER attn

// ---------------- fused weight transposes (one launch) ----------------
// blocks: [0,1296) conv | [1296,1440) q | [1440,1728) kv | [1728,1872) sr
__global__ __launch_bounds__(256) void k_wt_all(
    const float* __restrict__ pw, const float* __restrict__ qw,
    const float* __restrict__ kvw, const float* __restrict__ srw,
    float* __restrict__ w) {
  int gb = blockIdx.x;
  int tid = threadIdx.x;
  if (gb < 1296) {
    int i = gb * 256 + tid;
    int oc = i % 192, k = i / 192;
    w[OFF_WTC + i] = pw[(size_t)oc * 1728 + k];
  } else if (gb < 1440) {
    int i = (gb - 1296) * 256 + tid;
    int o = i % 192, k = i / 192;
    w[OFF_QT + i] = qw[(size_t)o * 192 + k];
  } else if (gb < 1728) {
    int i = (gb - 1440) * 256 + tid;
    int o = i % 384, k = i / 384;
    w[OFF_KVT + i] = kvw[(size_t)o * 192 + k];
  } else {
    int i = (gb - 1728) * 256 + tid;
    int o = i % 192, k = i / 192;
    w[OFF_SRT + i] = srw[(size_t)o * 192 + k];
  }
}
__global__ __launch_bounds__(256) void k_wt_gen(const float* __restrict__ src,
                                                float* __restrict__ dst, int O, int K) {
  int i = blockIdx.x * 256 + threadIdx.x;
  if (i >= O * K) return;
  int o = i % O, k = i / O;
  dst[i] = src[(size_t)o * K + k];
}

// ---------------- 3x3 conv; split-K thirds (64 ic), 4 rows/lane, 12 oc/wave ----------
// (round-7 proven structure: weights via wave-uniform scalar loads, [k][192] layout)
__global__ __launch_bounds__(256) void k_conv(
    const float* __restrict__ x, const float* __restrict__ wtc,
    float* __restrict__ p0, float* __restrict__ p1, float* __restrict__ p2) {
  __shared__ float xl[8 * 6 * 66];              // 12.4 KB [ii][r(6)][wp]
  const int tid = threadIdx.x;
  const int lane = tid & 63;
  const int wv = __builtin_amdgcn_readfirstlane(tid >> 6);
  const int h0 = blockIdx.x * 4;                // 4 output rows per block
  const int b = blockIdx.y;
  const int zz = blockIdx.z;
  const int obase = (zz & 3) * 48;
  const int ith = zz >> 2;                      // ic third 0..2
  const int icb = ith * 8;                      // 8 ic-groups of 8 = 64 ics
  const int ow = obase + wv * 12;

  float acc[4][12];
#pragma unroll
  for (int ro = 0; ro < 4; ++ro)
#pragma unroll
    for (int j = 0; j < 12; ++j) acc[ro][j] = 0.f;

  float xr[13];
  auto loadx = [&](int ic0) {
#pragma unroll
    for (int s = 0; s < 13; ++s) {
      int f = tid + s * 256;
      float v = 0.f;
      if (f < 3168) {
        int ii = f / 396;
        int rem = f - ii * 396;
        int r = rem / 66;
        int wp = rem - r * 66;
        int hh = h0 + r - 1, ww = wp - 1;
        if (hh >= 0 && hh < 64 && ww >= 0 && ww < 64)
          v = x[((size_t)(b * 192 + ic0 * 8 + ii) << 12) + (hh << 6) + ww];
      }
      xr[s] = v;
    }
  };
  loadx(icb);

  for (int i2 = 0; i2 < 8; ++i2) {
    const int ic0 = icb + i2;
    __syncthreads();
#pragma unroll
    for (int s = 0; s < 13; ++s) {
      int f = tid + s * 256;
      if (f < 3168) {
        int ii = f / 396;
        int rem = f - ii * 396;
        int r = rem / 66;
        int wp = rem - r * 66;
        xl[(ii * 6 + r) * 66 + wp] = xr[s];
      }
    }
    __syncthreads();
    if (i2 < 7) loadx(ic0 + 1);
    const float* wb = wtc + (size_t)ic0 * 72 * 192 + ow;   // wave-uniform base
#pragma unroll 1
    for (int ii = 0; ii < 8; ++ii) {
      // register-cache the 6 LDS rows (3 taps each) for this input channel
      float xv[6][3];
#pragma unroll
      for (int r6 = 0; r6 < 6; ++r6) {
        const float* xp = &xl[(ii * 6 + r6) * 66 + lane];
        xv[r6][0] = xp[0]; xv[r6][1] = xp[1]; xv[r6][2] = xp[2];
      }
#pragma unroll
      for (int kh = 0; kh < 3; ++kh) {
#pragma unroll
        for (int kw = 0; kw < 3; ++kw) {
          const float4* wp = (const float4*)(wb + (size_t)(ii * 9 + kh * 3 + kw) * 192);
          float4 wA = wp[0], wB = wp[1], wC = wp[2];
#pragma unroll
          for (int ro = 0; ro < 4; ++ro) {
            float xvv = xv[ro + kh][kw];
            acc[ro][0]  += xvv * wA.x;
            acc[ro][1]  += xvv * wA.y;
            acc[ro][2]  += xvv * wA.z;
            acc[ro][3]  += xvv * wA.w;
            acc[ro][4]  += xvv * wB.x;
            acc[ro][5]  += xvv * wB.y;
            acc[ro][6]  += xvv * wB.z;
            acc[ro][7]  += xvv * wB.w;
            acc[ro][8]  += xvv * wC.x;
            acc[ro][9]  += xvv * wC.y;
            acc[ro][10] += xvv * wC.z;
            acc[ro][11] += xvv * wC.w;
          }
        }
      }
    }
  }
  float* tdst = (ith == 0) ? p0 : ((ith == 1) ? p1 : p2);
#pragma unroll
  for (int ro = 0; ro < 4; ++ro) {
    float* op = tdst + ((size_t)b * 4096 + (h0 + ro) * 64 + lane) * 192 + ow;
#pragma unroll
    for (int j4 = 0; j4 < 3; ++j4) {
      float4 v;
      v.x = acc[ro][j4 * 4 + 0];
      v.y = acc[ro][j4 * 4 + 1];
      v.z = acc[ro][j4 * 4 + 2];
      v.w = acc[ro][j4 * 4 + 3];
      ((float4*)op)[j4] = v;
    }
  }
}

// ---------------- LN over 192 channels (wave per row) ----------------
__global__ __launch_bounds__(256) void k_ln_rows(float* __restrict__ data,
    const float* __restrict__ data2, const float* __restrict__ data3,
    const float* __restrict__ cbias,
    const float* __restrict__ g, const float* __restrict__ be, int rows) {
  int lane = threadIdx.x & 63;
  int wv = threadIdx.x >> 6;
  int row = blockIdx.x * 4 + wv;
  if (row >= rows) return;
  float* p = data + (size_t)row * 192;
  float v0 = p[lane], v1 = p[lane + 64], v2 = p[lane + 128];
  if (data2) {
    const float* q = data2 + (size_t)row * 192;
    v0 += q[lane]; v1 += q[lane + 64]; v2 += q[lane + 128];
  }
  if (data3) {
    const float* q = data3 + (size_t)row * 192;
    v0 += q[lane]; v1 += q[lane + 64]; v2 += q[lane + 128];
  }
  if (cbias) {
    v0 += cbias[lane]; v1 += cbias[lane + 64]; v2 += cbias[lane + 128];
  }
  float s = v0 + v1 + v2;
  float sq = v0 * v0 + v1 * v1 + v2 * v2;
#pragma unroll
  for (int m = 32; m >= 1; m >>= 1) {
    s += __shfl_xor(s, m, 64);
    sq += __shfl_xor(sq, m, 64);
  }
  float mean = s * (1.f / 192.f);
  float var = sq * (1.f / 192.f) - mean * mean;
  float rstd = rsqrtf(var + 1e-5f);
  p[lane]       = (v0 - mean) * rstd * g[lane]       + be[lane];
  p[lane + 64]  = (v1 - mean) * rstd * g[lane + 64]  + be[lane + 64];
  p[lane + 128] = (v2 - mean) * rstd * g[lane + 128] + be[lane + 128];
}

// ======== GEMM tile core: x through LDS, weights via wave-uniform scalar loads ========
template <int OCB, typename GXV, typename GXD>
__device__ __forceinline__ void gemm_tiles(
    float* __restrict__ xs, int tid, int lane, int wv,
    const float* __restrict__ wt, int ostr, int obase,
    float (&acc)[OCB / 4], GXV gxv, GXD gxd) {
  constexpr int NW4 = OCB / 16;       // float4s per wave per kk
  float xr[8];
  auto loadx = [&](int k0) {
#pragma unroll
    for (int s = 0; s < 8; ++s) xr[s] = gxv(k0, tid + s * 256);
  };
  loadx(0);
  for (int kt = 0; kt < 6; ++kt) {
    __syncthreads();
#pragma unroll
    for (int s = 0; s < 8; ++s) xs[gxd(tid + s * 256)] = xr[s];
    __syncthreads();
    if (kt < 5) loadx((kt + 1) * 32);
    const float* wbase = wt + (size_t)kt * 32 * ostr + obase + wv * (NW4 * 4);
#pragma unroll 4
    for (int kk = 0; kk < 32; ++kk) {
      float xv = xs[kk * 66 + lane];
      const float4* wrow = (const float4*)(wbase + (size_t)kk * ostr);
#pragma unroll
      for (int j4 = 0; j4 < NW4; ++j4) {
        float4 w4 = wrow[j4];
        acc[j4 * 4 + 0] += xv * w4.x;
        acc[j4 * 4 + 1] += xv * w4.y;
        acc[j4 * 4 + 2] += xv * w4.z;
        acc[j4 * 4 + 3] += xv * w4.w;
      }
    }
  }
}

// ---------------- q GEMM (96 oc = 4 heads/block) -> l2norm -> scaled ----------------
__global__ __launch_bounds__(256) void k_q(
    const float* __restrict__ t, const float* __restrict__ qt, const float* __restrict__ qb,
    const float* __restrict__ qe, const float* __restrict__ tmp, const float* __restrict__ ss,
    float* __restrict__ qno, float* __restrict__ qso) {
  __shared__ float xs[32 * 66];
  const int tid = threadIdx.x;
  const int lane = tid & 63;
  const int wv = __builtin_amdgcn_readfirstlane(tid >> 6);
  const int n0 = blockIdx.x * 64;
  const int b = blockIdx.y;
  const int obase = blockIdx.z * 96;
  const int hh = blockIdx.z * 4 + wv;
  const int oc0 = obase + wv * 24;
  float acc[24];
#pragma unroll
  for (int j = 0; j < 24; ++j) acc[j] = 0.f;

  gemm_tiles<96>(xs, tid, lane, wv, qt, 192, obase, acc,
    [&](int k0, int f) {
      int nl = f >> 5, kk = f & 31;
      return t[((size_t)b * 4096 + n0 + nl) * 192 + k0 + kk];
    },
    [&](int f) { return (f & 31) * 66 + (f >> 5); });

  const int n = n0 + lane;
  float ssv = ss[n];
  float sumsq = 0.f;
#pragma unroll
  for (int d = 0; d < 24; ++d) {
    float v = acc[d] + qb[oc0 + d];
    sumsq += v * v;
  }
  float rn = 1.f / fmaxf(sqrtf(sumsq), 1e-12f);
  float sp = log1pf(__expf(tmp[hh]));
#pragma unroll
  for (int d = 0; d < 24; ++d) {
    float qv = (acc[d] + qb[oc0 + d]) * rn;
    size_t o = ((size_t)(b * 8 + hh) * 24 + d) * 4096 + n;
    qno[o] = qv;
    qso[o] = (qv + qe[hh * 24 + d]) * sp * ssv;
  }
}

// ---------------- kv GEMM (96 of 384 oc/block) -> kmap[b][c][n] ----------------
__global__ __launch_bounds__(256) void k_kv(
    const float* __restrict__ t, const float* __restrict__ kvt, const float* __restrict__ kb_,
    float* __restrict__ kmap) {
  __shared__ float xs[32 * 66];
  const int tid = threadIdx.x;
  const int lane = tid & 63;
  const int wv = __builtin_amdgcn_readfirstlane(tid >> 6);
  const int n0 = blockIdx.x * 64;
  const int b = blockIdx.y;
  const int obase = blockIdx.z * 96;
  const int oc0 = obase + wv * 24;
  const int n = n0 + lane;
  float acc[24];
#pragma unroll
  for (int j = 0; j < 24; ++j) acc[j] = 0.f;

  gemm_tiles<96>(xs, tid, lane, wv, kvt, 384, obase, acc,
    [&](int k0, int f) {
      int nl = f >> 5, kk = f & 31;
      return t[((size_t)b * 4096 + n0 + nl) * 192 + k0 + kk];
    },
    [&](int f) { return (f & 31) * 66 + (f >> 5); });

  if (oc0 < 192) {
    float sumsq = 0.f;
#pragma unroll
    for (int d = 0; d < 24; ++d) {
      float v = acc[d] + kb_[oc0 + d];
      sumsq += v * v;
    }
    float rn = 1.f / fmaxf(sqrtf(sumsq), 1e-12f);
#pragma unroll
    for (int d = 0; d < 24; ++d)
      kmap[((size_t)b * 384 + oc0 + d) * 4096 + n] = (acc[d] + kb_[oc0 + d]) * rn;
  } else {
#pragma unroll
    for (int d = 0; d < 24; ++d)
      kmap[((size_t)b * 384 + oc0 + d) * 4096 + n] = acc[d] + kb_[oc0 + d];
  }
}

// ---------------- sr GEMM (48 oc/block) + exact gelu + 4x4 mean-pool ----------------
__device__ __forceinline__ float gelu_exact(float v) {
  float u = v * 0.70710678118654752f;
  float a = fabsf(u);
  float tt = 1.f / (1.f + 0.3275911f * a);
  float poly = ((((1.061405429f * tt - 1.453152027f) * tt + 1.421413741f) * tt
                 - 0.284496736f) * tt + 0.254829592f) * tt;
  float erfa = 1.f - poly * __expf(-a * a);
  float erfv = (u < 0.f) ? -erfa : erfa;
  return 0.5f * v * (1.f + erfv);
}

__global__ __launch_bounds__(256) void k_srpool(
    const float* __restrict__ t, const float* __restrict__ srt, const float* __restrict__ sb,
    float* __restrict__ pooled) {
  __shared__ float xs[32 * 66];
  const int tid = threadIdx.x;
  const int lane = tid & 63;
  const int wv = __builtin_amdgcn_readfirstlane(tid >> 6);
  const int wx = blockIdx.x & 3;
  const int obase = (blockIdx.x >> 2) * 48;
  const int ph = blockIdx.y;
  const int b = blockIdx.z;
  const int oc0 = obase + wv * 12;
  float acc[12];
#pragma unroll
  for (int j = 0; j < 12; ++j) acc[j] = 0.f;

  gemm_tiles<48>(xs, tid, lane, wv, srt, 192, obase, acc,
    [&](int k0, int f) {
      int pl = f >> 5, kk = f & 31;
      int row = (ph * 4 + (pl >> 4)) * 64 + wx * 16 + (pl & 15);
      return t[((size_t)b * 4096 + row) * 192 + k0 + kk];
    },
    [&](int f) { return (f & 31) * 66 + (f >> 5); });

#pragma unroll
  for (int j = 0; j < 12; ++j) {
    float gv = gelu_exact(acc[j] + sb[oc0 + j]);
    gv += __shfl_xor(gv, 1, 64);
    gv += __shfl_xor(gv, 2, 64);
    gv += __shfl_xor(gv, 16, 64);
    gv += __shfl_xor(gv, 32, 64);
    if ((lane & 51) == 0) {
      int cell = (lane >> 2) & 3;
      int p = ph * 16 + wx * 4 + cell;
      pooled[((size_t)b * 256 + p) * 192 + oc0 + j] = gv * (1.f / 16.f);
    }
  }
}

// ---------------- pooled kv (96 of 384 oc/block) -> kp/vp [b][h][m][24] ----------------
__global__ __launch_bounds__(256) void k_kvp(
    const float* __restrict__ pooled, const float* __restrict__ kvt, const float* __restrict__ kb_,
    float* __restrict__ kp, float* __restrict__ vp) {
  __shared__ float xs[32 * 66];
  const int tid = threadIdx.x;
  const int lane = tid & 63;
  const int wv = __builtin_amdgcn_readfirstlane(tid >> 6);
  const int r0 = blockIdx.x * 64;
  const int obase = blockIdx.y * 96;
  const int oc0 = obase + wv * 24;
  const int row = r0 + lane;
  const int b = row >> 8;
  const int m = row & 255;
  float acc[24];
#pragma unroll
  for (int j = 0; j < 24; ++j) acc[j] = 0.f;

  gemm_tiles<96>(xs, tid, lane, wv, kvt, 384, obase, acc,
    [&](int k0, int f) {
      int nl = f >> 5, kk = f & 31;
      return pooled[(size_t)(r0 + nl) * 192 + k0 + kk];
    },
    [&](int f) { return (f & 31) * 66 + (f >> 5); });

  if (oc0 < 192) {
    int hh = oc0 / 24;
    float sumsq = 0.f;
#pragma unroll
    for (int d = 0; d < 24; ++d) {
      float v = acc[d] + kb_[oc0 + d];
      sumsq += v * v;
    }
    float rn = 1.f / fmaxf(sqrtf(sumsq), 1e-12f);
#pragma unroll
    for (int d = 0; d < 24; ++d)
      kp[(((size_t)(b * 8 + hh)) * 256 + m) * 24 + d] = (acc[d] + kb_[oc0 + d]) * rn;
  } else {
    int hh = (oc0 - 192) / 24;
#pragma unroll
    for (int d = 0; d < 24; ++d)
      vp[(((size_t)(b * 8 + hh)) * 256 + m) * 24 + d] = acc[d] + kb_[oc0 + d];
  }
}

// ---------------- cpb MLP: (T,2) -> (T,8), weights staged in LDS ----------------
__global__ __launch_bounds__(256) void k_cpb(
    const float* __restrict__ coords, const float* __restrict__ c1w,
    const float* __restrict__ c1b, const float* __restrict__ c2w,
    const float* __restrict__ c2b, float* __restrict__ cpb, int T) {
  __shared__ float s1w[1024];     // [j][2]
  __shared__ float s1b[512];
  __shared__ __align__(16) float s2w[512 * 8];  // [j][h]
  const int tid = threadIdx.x;
  for (int f = tid; f < 1024; f += 256) s1w[f] = c1w[f];
  for (int f = tid; f < 512; f += 256) s1b[f] = c1b[f];
  for (int f = tid; f < 4096; f += 256) {
    int h = f >> 9, j = f & 511;
    s2w[j * 8 + h] = c2w[f];
  }
  __syncthreads();
  int i = blockIdx.x * 256 + tid;
  int ic = (i < T) ? i : (T - 1);
  float x0 = coords[2 * ic], y0 = coords[2 * ic + 1];
  float a[8];
#pragma unroll
  for (int h = 0; h < 8; ++h) a[h] = c2b[h];
#pragma unroll 4
  for (int j = 0; j < 512; ++j) {
    float hv = fmaxf(s1w[2 * j] * x0 + s1w[2 * j + 1] * y0 + s1b[j], 0.f);
    const float4* w2 = (const float4*)&s2w[j * 8];
    float4 wA = w2[0], wB = w2[1];
    a[0] += hv * wA.x; a[1] += hv * wA.y; a[2] += hv * wA.z; a[3] += hv * wA.w;
    a[4] += hv * wB.x; a[5] += hv * wB.y; a[6] += hv * wB.z; a[7] += hv * wB.w;
  }
  if (i < T) {
#pragma unroll
    for (int h = 0; h < 8; ++h) cpb[(size_t)i * 8 + h] = a[h];
  }
}

// ---------------- pool bias gather: bt[h][n][m] (bf16, m-contiguous) ----------------
__global__ __launch_bounds__(256) void k_bias(
    const int* __restrict__ rel, const float* __restrict__ cpb,
    unsigned short* __restrict__ bt) {
  int g = blockIdx.x * 256 + threadIdx.x;   // 131072 total = 4096 n * 32 chunks
  int n = g >> 5;
  int m0 = (g & 31) * 8;
  const int4* r4 = (const int4*)(rel + (size_t)n * 256 + m0);
  int4 ra = r4[0], rb = r4[1];
  int idxs[8] = {ra.x, ra.y, ra.z, ra.w, rb.x, rb.y, rb.z, rb.w};
  unsigned acc[8][4];
#pragma unroll
  for (int j = 0; j < 8; ++j) {
    const float4* c4 = (const float4*)(cpb + (size_t)idxs[j] * 8);
    float4 A = c4[0], Bv = c4[1];
    float vals[8] = {A.x, A.y, A.z, A.w, Bv.x, Bv.y, Bv.z, Bv.w};
#pragma unroll
    for (int hh = 0; hh < 8; ++hh) {
      unsigned u = f2b(vals[hh]);
      if (j & 1) acc[hh][j >> 1] |= u << 16;
      else       acc[hh][j >> 1]  = u;
    }
  }
#pragma unroll
  for (int hh = 0; hh < 8; ++hh) {
    uint4 o;
    o.x = acc[hh][0]; o.y = acc[hh][1]; o.z = acc[hh][2]; o.w = acc[hh][3];
    *(uint4*)(bt + ((size_t)hh * 4096 + n) * 256 + m0) = o;
  }
}

// ---------------- fused attention; 512 threads = 2 rows x 4 m-quarter waves ----------------
// Pooled-phase kp/vp now read via WAVE-UNIFORM scalar loads straight from global
// (L2-resident, 24 KB per (b,h)) -- no LDS staging, no staging barrier, LDS is
// only the 25 KB cross-quarter reduction buffer.
__global__ __launch_bounds__(512, 4) void k_attn(
    const float* __restrict__ qs_g, const float* __restrict__ qn_g,
    const float* __restrict__ kmap, const float* __restrict__ kp, const float* __restrict__ vp,
    const unsigned short* __restrict__ bt, const float* __restrict__ rpb,
    const float* __restrict__ lt, const float* __restrict__ lb,
    float* __restrict__ ctx) {
  __shared__ float smem[6272];   // 128 x 49 reduction buffer (stride 49: odd, conflict-free)
  const int tid = threadIdx.x;
  const int lane = tid & 63;
  const int w = __builtin_amdgcn_readfirstlane(tid >> 6);
  const int qm = w & 3;          // m-quarter / local-tap subset
  const int rr = w >> 2;         // row within the pair
  const int row = blockIdx.x * 2 + rr;
  const int h = blockIdx.y;
  const int b = blockIdx.z;
  const int n = (row << 6) + lane;
  const float SHIFT = 15.f;

  float qsv[24];
  {
    const float* qsb = qs_g + ((size_t)(b * 8 + h) * 24) * 4096 + n;
#pragma unroll
    for (int d = 0; d < 24; ++d) qsv[d] = qsb[(size_t)d * 4096];
  }

  // local-tap subsets: qm1 -> {0,1,2}; qm0 -> {3,4}; qm2 -> {5,6}; qm3 -> {7,8}
  const int l0 = (qm == 1) ? 0 : ((qm == 0) ? 3 : (qm * 2 + 1));
  const int lcnt = (qm == 1) ? 3 : 2;

  float wlv[3];
  {
    float qnv[24];
    const float* qnb = qn_g + ((size_t)(b * 8 + h) * 24) * 4096 + n;
#pragma unroll
    for (int d = 0; d < 24; ++d) qnv[d] = qnb[(size_t)d * 4096];
    const float* ltp = lt + h * 216;
    const float* lbp = lb + h * 9;
#pragma unroll
    for (int j = 0; j < 3; ++j) {
      float a = 0.f;
      if (j < lcnt) {
        int l = l0 + j;
#pragma unroll
        for (int d = 0; d < 24; ++d) a += qnv[d] * ltp[d * 9 + l];
        a += lbp[l];
      }
      wlv[j] = a;
    }
  }

  float ctxA[24], ctxBP[24];
#pragma unroll
  for (int d = 0; d < 24; ++d) { ctxA[d] = 0.f; ctxBP[d] = 0.f; }
  float S = 0.f;

  // local window (this wave's tap subset); row is wave-uniform
  {
    const float* kbase = kmap + ((size_t)b * 384 + h * 24) * 4096;
    const float* rpp = rpb + h * 9;
    for (int j = 0; j < lcnt; ++j) {
      const int l = l0 + j;
      const int dh = l / 3 - 1, dw = l % 3 - 1;
      const int hp = row + dh;
      if (hp < 0 || hp >= 64) continue;        // wave-uniform branch
      const int wp2 = lane + dw;
      const bool okw = (wp2 >= 0) && (wp2 < 64);
      const int nn = (hp << 6) + (okw ? wp2 : lane);  // clamped safe addr
      const float* kb = kbase + nn;
      const float* vb = kb + (size_t)192 * 4096;
      float d0 = 0, d1 = 0, d2 = 0, d3 = 0;
#pragma unroll
      for (int d = 0; d < 24; d += 4) {
        d0 += qsv[d] * kb[(size_t)d * 4096];
        d1 += qsv[d + 1] * kb[(size_t)(d + 1) * 4096];
        d2 += qsv[d + 2] * kb[(size_t)(d + 2) * 4096];
        d3 += qsv[d + 3] * kb[(size_t)(d + 3) * 4096];
      }
      float p = okw ? __expf((d0 + d1) + (d2 + d3) + rpp[l] - SHIFT) : 0.f;
      S += p;
      float wll = okw ? wlv[j] : 0.f;
#pragma unroll
      for (int d = 0; d < 24; ++d) {
        float vv = vb[(size_t)d * 4096];
        ctxA[d] += wll * vv;
        ctxBP[d] += p * vv;
      }
    }
  }

  // pooled keys: this wave's 64-m quarter; k/v via wave-uniform scalar loads,
  // bias loaded as per-lane uint4 with 1-chunk prefetch (vmem path, separate counter)
  {
    const unsigned short* bp = bt + ((size_t)h * 4096 + n) * 256 + qm * 64;
    const float* kq = kp + (size_t)((b * 8 + h) * 256 + qm * 64) * 24;
    const float* vq = vp + (size_t)((b * 8 + h) * 256 + qm * 64) * 24;
    uint4 bcur = *(const uint4*)bp;
#pragma unroll 1
    for (int c = 0; c < 8; ++c) {
      uint4 bnx = bcur;
      if (c < 7) bnx = *(const uint4*)(bp + (c + 1) * 8);
#pragma unroll
      for (int j = 0; j < 8; ++j) {
        const float4* kr4 = (const float4*)(kq + (size_t)(c * 8 + j) * 24);
        const float4* vr4 = (const float4*)(vq + (size_t)(c * 8 + j) * 24);
        float d0 = 0, d1 = 0, d2 = 0, d3 = 0;
#pragma unroll
        for (int q4 = 0; q4 < 6; ++q4) {
          float4 k4 = kr4[q4];
          d0 += qsv[q4 * 4 + 0] * k4.x;
          d1 += qsv[q4 * 4 + 1] * k4.y;
          d2 += qsv[q4 * 4 + 2] * k4.z;
          d3 += qsv[q4 * 4 + 3] * k4.w;
        }
        unsigned word = (j < 2) ? bcur.x : (j < 4) ? bcur.y : (j < 6) ? bcur.z : bcur.w;
        float bv = (j & 1) ? __uint_as_float(word & 0xffff0000u)
                           : __uint_as_float(word << 16);
        float p = __expf((d0 + d1) + (d2 + d3) + bv - SHIFT);
        S += p;
#pragma unroll
        for (int q4 = 0; q4 < 6; ++q4) {
          float4 v4 = vr4[q4];
          ctxBP[q4 * 4 + 0] += p * v4.x;
          ctxBP[q4 * 4 + 1] += p * v4.y;
          ctxBP[q4 * 4 + 2] += p * v4.z;
          ctxBP[q4 * 4 + 3] += p * v4.w;
        }
      }
      bcur = bnx;
    }
  }

  // cross-quarter reduction (stride 49 floats: odd -> bank-conflict-free)
  for (int src = 1; src < 4; ++src) {
    __syncthreads();
    if (qm == src) {
      float* p = smem + (size_t)(rr * 64 + lane) * 49;
      p[0] = S;
#pragma unroll
      for (int d = 0; d < 24; ++d) { p[1 + d] = ctxA[d]; p[25 + d] = ctxBP[d]; }
    }
    __syncthreads();
    if (qm == 0) {
      const float* p = smem + (size_t)(rr * 64 + lane) * 49;
      S += p[0];
#pragma unroll
      for (int d = 0; d < 24; ++d) { ctxA[d] += p[1 + d]; ctxBP[d] += p[25 + d]; }
    }
  }
  if (qm == 0) {
    const float inv = 1.f / S;
    float* cb = ctx + ((size_t)(b * 8 + h) * 24) * 4096 + n;
#pragma unroll
    for (int d = 0; d < 24; ++d)
      cb[(size_t)d * 4096] = ctxA[d] + ctxBP[d] * inv;
  }
}

// ---------------- fused proj GEMM + output LN; 512 threads = 8 waves x 24 oc ----------
__global__ __launch_bounds__(512) void k_projoln(
    const float* __restrict__ ctx, const float* __restrict__ pjt, const float* __restrict__ pb,
    const float* __restrict__ g, const float* __restrict__ be, float* __restrict__ out) {
  __shared__ float xs[32 * 66];
  __shared__ float red[2][8][64];
  const int tid = threadIdx.x;
  const int lane = tid & 63;
  const int wv = __builtin_amdgcn_readfirstlane(tid >> 6);   // 0..7
  const int n0 = blockIdx.x * 64;
  const int b = blockIdx.y;
  const int oc0 = wv * 24;
  float acc[24];
#pragma unroll
  for (int j = 0; j < 24; ++j) acc[j] = 0.f;

  float xr[4];
  auto loadx = [&](int k0) {
#pragma unroll
    for (int s = 0; s < 4; ++s) {
      int f = tid + s * 512;
      int kk = f >> 6, nl = f & 63;
      xr[s] = ctx[((size_t)b * 192 + k0 + kk) * 4096 + n0 + nl];
    }
  };
  loadx(0);
  for (int kt = 0; kt < 6; ++kt) {
    __syncthreads();
#pragma unroll
    for (int s = 0; s < 4; ++s) {
      int f = tid + s * 512;
      xs[(f >> 6) * 66 + (f & 63)] = xr[s];
    }
    __syncthreads();
    if (kt < 5) loadx((kt + 1) * 32);
    const float* wbase = pjt + (size_t)kt * 32 * 192 + oc0;
#pragma unroll 4
    for (int kk = 0; kk < 32; ++kk) {
      float xv = xs[kk * 66 + lane];
      const float4* wrow = (const float4*)(wbase + (size_t)kk * 192);
#pragma unroll
      for (int j4 = 0; j4 < 6; ++j4) {
        float4 w4 = wrow[j4];
        acc[j4 * 4 + 0] += xv * w4.x;
        acc[j4 * 4 + 1] += xv * w4.y;
        acc[j4 * 4 + 2] += xv * w4.z;
        acc[j4 * 4 + 3] += xv * w4.w;
      }
    }
  }

  // bias + LN partials
  float v[24];
  float s = 0.f, sq = 0.f;
#pragma unroll
  for (int d = 0; d < 24; ++d) {
    v[d] = acc[d] + pb[oc0 + d];
    s += v[d];
    sq += v[d] * v[d];
  }
  red[0][wv][lane] = s;
  red[1][wv][lane] = sq;
  __syncthreads();
  float st = 0.f, sqt = 0.f;
#pragma unroll
  for (int k = 0; k < 8; ++k) {
    st += red[0][k][lane];
    sqt += red[1][k][lane];
  }
  float mean = st * (1.f / 192.f);
  float var = sqt * (1.f / 192.f) - mean * mean;
  float rstd = rsqrtf(var + 1e-5f);
#pragma unroll
  for (int d = 0; d < 24; ++d) {
    int o = oc0 + d;
    out[((size_t)b * 192 + o) * 4096 + n0 + lane] = (v[d] - mean) * rstd * g[o] + be[o];
  }
}

// ---------------- host launcher ----------------
extern "C" void kernel_launch(void* const* d_in, const int* in_sizes, int n_in,
                              void* d_out, int out_size, void* d_ws, size_t ws_size,
                              hipStream_t stream) {
  float* w = (float*)d_ws;

  const float* x      = (const float*)d_in[0];
  const float* pe_w   = (const float*)d_in[1];
  const float* pe_b   = (const float*)d_in[2];
  const float* peln_g = (const float*)d_in[3];
  const float* peln_b = (const float*)d_in[4];
  const float* q_w    = (const float*)d_in[5];
  const float* q_b    = (const float*)d_in[6];
  const float* kv_w   = (const float*)d_in[7];
  const float* kv_b   = (const float*)d_in[8];
  const float* sr_w   = (const float*)d_in[9];
  const float* sr_b   = (const float*)d_in[10];
  const float* norm_g = (const float*)d_in[11];
  const float* norm_b = (const float*)d_in[12];
  const float* cpb1w  = (const float*)d_in[13];
  const float* cpb1b  = (const float*)d_in[14];
  const float* cpb2w  = (const float*)d_in[15];
  const float* cpb2b  = (const float*)d_in[16];
  const float* rpb    = (const float*)d_in[17];
  const float* lt     = (const float*)d_in[18];
  const float* lb     = (const float*)d_in[19];
  const float* qe     = (const float*)d_in[20];
  const float* temp   = (const float*)d_in[21];
  const float* proj_w = (const float*)d_in[22];
  const float* proj_b = (const float*)d_in[23];
  const float* oln_g  = (const float*)d_in[24];
  const float* oln_b  = (const float*)d_in[25];
  const int*   rel    = (const int*)d_in[26];
  const float* coords = (const float*)d_in[27];
  const float* ss     = (const float*)d_in[28];

  dim3 blk(256);
  // all four weight transposes in one launch
  k_wt_all<<<dim3(1872), blk, 0, stream>>>(pe_w, q_w, kv_w, sr_w, w);

  // split-K conv: z = 4 oc-blocks x 3 ic-thirds; partials -> T, KMAP, KMAP+3145728
  k_conv<<<dim3(16, 4, 12), blk, 0, stream>>>(x, w + OFF_WTC, w + OFF_T,
      w + OFF_KMAP, w + OFF_KMAP + 3145728);
  // merge partials + conv bias + LN
  k_ln_rows<<<dim3(4096), blk, 0, stream>>>(w + OFF_T, w + OFF_KMAP,
      w + OFF_KMAP + 3145728, pe_b, peln_g, peln_b, 16384);
  k_q<<<dim3(64, 4, 2), blk, 0, stream>>>(w + OFF_T, w + OFF_QT, q_b, qe, temp, ss,
      w + OFF_QN, w + OFF_QS);
  k_kv<<<dim3(64, 4, 4), blk, 0, stream>>>(w + OFF_T, w + OFF_KVT, kv_b, w + OFF_KMAP);
  k_srpool<<<dim3(16, 16, 4), blk, 0, stream>>>(w + OFF_T, w + OFF_SRT, sr_b, w + OFF_POOL);
  k_ln_rows<<<dim3(256), blk, 0, stream>>>(w + OFF_POOL, nullptr, nullptr, nullptr,
      norm_g, norm_b, 1024);
  k_kvp<<<dim3(16, 4), blk, 0, stream>>>(w + OFF_POOL, w + OFF_KVT, kv_b,
      w + OFF_KP, w + OFF_VP);
  int T = in_sizes[27] / 2;
  k_cpb<<<dim3((T + 255) / 256), blk, 0, stream>>>(coords, cpb1w, cpb1b, cpb2w, cpb2b,
      w + OFF_CPB, T);
  k_bias<<<dim3(512), blk, 0, stream>>>(rel, w + OFF_CPB,
      (unsigned short*)(w + OFF_BIAS));
  k_attn<<<dim3(32, 8, 4), dim3(512), 0, stream>>>(w + OFF_QS, w + OFF_QN, w + OFF_KMAP,
      w + OFF_KP, w + OFF_VP, (const unsigned short*)(w + OFF_BIAS), rpb, lt, lb,
      w + OFF_CTX);
  k_wt_gen<<<dim3(144), blk, 0, stream>>>(proj_w, w + OFF_PJT, 192, 192);
  // fused proj GEMM + output LN -> d_out (no pout round-trip)
  k_projoln<<<dim3(64, 4), dim3(512), 0, stream>>>(w + OFF_CTX, w + OFF_PJT, proj_b,
      oln_g, oln_b, (float*)d_out);
}

// Round 12
// 502.798 us; speedup vs baseline: 1.1131x; 1.1131x over previous
//
#include <hip/hip_runtime.h>
#include <stdint.h>

// B=4, DIM=192, H=W=64, N=4096, HEADS=8, HD=24, SR=4, PLEN=256, LL=9
// All inputs f32, output f32.

__device__ __forceinline__ float b2f(unsigned short u) {
  return __uint_as_float(((unsigned)u) << 16);
}
__device__ __forceinline__ unsigned short f2b(float f) {
  unsigned x = __float_as_uint(f);
  return (unsigned short)((x + 0x7fffu + ((x >> 16) & 1u)) >> 16);
}

// ---------------- workspace layout (floats) ----------------
constexpr size_t OFF_T    = 0;          // (B,N,192)
constexpr size_t OFF_KMAP = 3145728;    // (B,384,N); early: conv partials 1+2
constexpr size_t OFF_QN   = 9437184;    // (B,8,24,N)
constexpr size_t OFF_QS   = 12582912;   // (B,8,24,N)
constexpr size_t OFF_CTX  = 15728640;   // (B,8,24,N)  (early: scratch for W transposes)
constexpr size_t OFF_POOL = 18874368;   // (B,256,192)
constexpr size_t OFF_KP   = 19070976;   // (B,8,256,24)
constexpr size_t OFF_VP   = 19267584;   // (B,8,256,24)
constexpr size_t OFF_CPB  = 19464192;   // (T,8)
constexpr size_t OFF_BIAS = 19595264;   // bf16 (8,4096,256) = 16.7 M ushort  [h][n][m]
constexpr size_t OFF_WTC  = OFF_CTX;              // conv wt [1728][192]
constexpr size_t OFF_QT   = OFF_CTX + 331776;     // [192][192]
constexpr size_t OFF_KVT  = OFF_CTX + 368640;     // [192][384]
constexpr size_t OFF_SRT  = OFF_CTX + 442368;     // [192][192]
constexpr size_t OFF_PJT  = OFF_KMAP;             // [192][192], created AFTER attn

// ---------------- fused weight transposes (one launch) ----------------
// blocks: [0,1296) conv | [1296,1440) q | [1440,1728) kv | [1728,1872) sr
__global__ __launch_bounds__(256) void k_wt_all(
    const float* __restrict__ pw, const float* __restrict__ qw,
    const float* __restrict__ kvw, const float* __restrict__ srw,
    float* __restrict__ w) {
  int gb = blockIdx.x;
  int tid = threadIdx.x;
  if (gb < 1296) {
    int i = gb * 256 + tid;
    int oc = i % 192, k = i / 192;
    w[OFF_WTC + i] = pw[(size_t)oc * 1728 + k];
  } else if (gb < 1440) {
    int i = (gb - 1296) * 256 + tid;
    int o = i % 192, k = i / 192;
    w[OFF_QT + i] = qw[(size_t)o * 192 + k];
  } else if (gb < 1728) {
    int i = (gb - 1440) * 256 + tid;
    int o = i % 384, k = i / 384;
    w[OFF_KVT + i] = kvw[(size_t)o * 192 + k];
  } else {
    int i = (gb - 1728) * 256 + tid;
    int o = i % 192, k = i / 192;
    w[OFF_SRT + i] = srw[(size_t)o * 192 + k];
  }
}
__global__ __launch_bounds__(256) void k_wt_gen(const float* __restrict__ src,
                                                float* __restrict__ dst, int O, int K) {
  int i = blockIdx.x * 256 + threadIdx.x;
  if (i >= O * K) return;
  int o = i % O, k = i / O;
  dst[i] = src[(size_t)o * K + k];
}

// ---------------- 3x3 conv; split-K thirds (64 ic), 4 rows/lane, 12 oc/wave ----------
// (round-7 proven structure: weights via wave-uniform scalar loads, [k][192] layout)
__global__ __launch_bounds__(256) void k_conv(
    const float* __restrict__ x, const float* __restrict__ wtc,
    float* __restrict__ p0, float* __restrict__ p1, float* __restrict__ p2) {
  __shared__ float xl[8 * 6 * 66];              // 12.4 KB [ii][r(6)][wp]
  const int tid = threadIdx.x;
  const int lane = tid & 63;
  const int wv = __builtin_amdgcn_readfirstlane(tid >> 6);
  const int h0 = blockIdx.x * 4;                // 4 output rows per block
  const int b = blockIdx.y;
  const int zz = blockIdx.z;
  const int obase = (zz & 3) * 48;
  const int ith = zz >> 2;                      // ic third 0..2
  const int icb = ith * 8;                      // 8 ic-groups of 8 = 64 ics
  const int ow = obase + wv * 12;

  float acc[4][12];
#pragma unroll
  for (int ro = 0; ro < 4; ++ro)
#pragma unroll
    for (int j = 0; j < 12; ++j) acc[ro][j] = 0.f;

  float xr[13];
  auto loadx = [&](int ic0) {
#pragma unroll
    for (int s = 0; s < 13; ++s) {
      int f = tid + s * 256;
      float v = 0.f;
      if (f < 3168) {
        int ii = f / 396;
        int rem = f - ii * 396;
        int r = rem / 66;
        int wp = rem - r * 66;
        int hh = h0 + r - 1, ww = wp - 1;
        if (hh >= 0 && hh < 64 && ww >= 0 && ww < 64)
          v = x[((size_t)(b * 192 + ic0 * 8 + ii) << 12) + (hh << 6) + ww];
      }
      xr[s] = v;
    }
  };
  loadx(icb);

  for (int i2 = 0; i2 < 8; ++i2) {
    const int ic0 = icb + i2;
    __syncthreads();
#pragma unroll
    for (int s = 0; s < 13; ++s) {
      int f = tid + s * 256;
      if (f < 3168) {
        int ii = f / 396;
        int rem = f - ii * 396;
        int r = rem / 66;
        int wp = rem - r * 66;
        xl[(ii * 6 + r) * 66 + wp] = xr[s];
      }
    }
    __syncthreads();
    if (i2 < 7) loadx(ic0 + 1);
    const float* wb = wtc + (size_t)ic0 * 72 * 192 + ow;   // wave-uniform base
#pragma unroll 1
    for (int ii = 0; ii < 8; ++ii) {
      // register-cache the 6 LDS rows (3 taps each) for this input channel
      float xv[6][3];
#pragma unroll
      for (int r6 = 0; r6 < 6; ++r6) {
        const float* xp = &xl[(ii * 6 + r6) * 66 + lane];
        xv[r6][0] = xp[0]; xv[r6][1] = xp[1]; xv[r6][2] = xp[2];
      }
#pragma unroll
      for (int kh = 0; kh < 3; ++kh) {
#pragma unroll
        for (int kw = 0; kw < 3; ++kw) {
          const float4* wp = (const float4*)(wb + (size_t)(ii * 9 + kh * 3 + kw) * 192);
          float4 wA = wp[0], wB = wp[1], wC = wp[2];
#pragma unroll
          for (int ro = 0; ro < 4; ++ro) {
            float xvv = xv[ro + kh][kw];
            acc[ro][0]  += xvv * wA.x;
            acc[ro][1]  += xvv * wA.y;
            acc[ro][2]  += xvv * wA.z;
            acc[ro][3]  += xvv * wA.w;
            acc[ro][4]  += xvv * wB.x;
            acc[ro][5]  += xvv * wB.y;
            acc[ro][6]  += xvv * wB.z;
            acc[ro][7]  += xvv * wB.w;
            acc[ro][8]  += xvv * wC.x;
            acc[ro][9]  += xvv * wC.y;
            acc[ro][10] += xvv * wC.z;
            acc[ro][11] += xvv * wC.w;
          }
        }
      }
    }
  }
  float* tdst = (ith == 0) ? p0 : ((ith == 1) ? p1 : p2);
#pragma unroll
  for (int ro = 0; ro < 4; ++ro) {
    float* op = tdst + ((size_t)b * 4096 + (h0 + ro) * 64 + lane) * 192 + ow;
#pragma unroll
    for (int j4 = 0; j4 < 3; ++j4) {
      float4 v;
      v.x = acc[ro][j4 * 4 + 0];
      v.y = acc[ro][j4 * 4 + 1];
      v.z = acc[ro][j4 * 4 + 2];
      v.w = acc[ro][j4 * 4 + 3];
      ((float4*)op)[j4] = v;
    }
  }
}

// ---------------- LN over 192 channels (wave per row) ----------------
__global__ __launch_bounds__(256) void k_ln_rows(float* __restrict__ data,
    const float* __restrict__ data2, const float* __restrict__ data3,
    const float* __restrict__ cbias,
    const float* __restrict__ g, const float* __restrict__ be, int rows) {
  int lane = threadIdx.x & 63;
  int wv = threadIdx.x >> 6;
  int row = blockIdx.x * 4 + wv;
  if (row >= rows) return;
  float* p = data + (size_t)row * 192;
  float v0 = p[lane], v1 = p[lane + 64], v2 = p[lane + 128];
  if (data2) {
    const float* q = data2 + (size_t)row * 192;
    v0 += q[lane]; v1 += q[lane + 64]; v2 += q[lane + 128];
  }
  if (data3) {
    const float* q = data3 + (size_t)row * 192;
    v0 += q[lane]; v1 += q[lane + 64]; v2 += q[lane + 128];
  }
  if (cbias) {
    v0 += cbias[lane]; v1 += cbias[lane + 64]; v2 += cbias[lane + 128];
  }
  float s = v0 + v1 + v2;
  float sq = v0 * v0 + v1 * v1 + v2 * v2;
#pragma unroll
  for (int m = 32; m >= 1; m >>= 1) {
    s += __shfl_xor(s, m, 64);
    sq += __shfl_xor(sq, m, 64);
  }
  float mean = s * (1.f / 192.f);
  float var = sq * (1.f / 192.f) - mean * mean;
  float rstd = rsqrtf(var + 1e-5f);
  p[lane]       = (v0 - mean) * rstd * g[lane]       + be[lane];
  p[lane + 64]  = (v1 - mean) * rstd * g[lane + 64]  + be[lane + 64];
  p[lane + 128] = (v2 - mean) * rstd * g[lane + 128] + be[lane + 128];
}

// ======== GEMM tile core: x through LDS, weights via wave-uniform scalar loads ========
template <int OCB, typename GXV, typename GXD>
__device__ __forceinline__ void gemm_tiles(
    float* __restrict__ xs, int tid, int lane, int wv,
    const float* __restrict__ wt, int ostr, int obase,
    float (&acc)[OCB / 4], GXV gxv, GXD gxd) {
  constexpr int NW4 = OCB / 16;       // float4s per wave per kk
  float xr[8];
  auto loadx = [&](int k0) {
#pragma unroll
    for (int s = 0; s < 8; ++s) xr[s] = gxv(k0, tid + s * 256);
  };
  loadx(0);
  for (int kt = 0; kt < 6; ++kt) {
    __syncthreads();
#pragma unroll
    for (int s = 0; s < 8; ++s) xs[gxd(tid + s * 256)] = xr[s];
    __syncthreads();
    if (kt < 5) loadx((kt + 1) * 32);
    const float* wbase = wt + (size_t)kt * 32 * ostr + obase + wv * (NW4 * 4);
#pragma unroll 4
    for (int kk = 0; kk < 32; ++kk) {
      float xv = xs[kk * 66 + lane];
      const float4* wrow = (const float4*)(wbase + (size_t)kk * ostr);
#pragma unroll
      for (int j4 = 0; j4 < NW4; ++j4) {
        float4 w4 = wrow[j4];
        acc[j4 * 4 + 0] += xv * w4.x;
        acc[j4 * 4 + 1] += xv * w4.y;
        acc[j4 * 4 + 2] += xv * w4.z;
        acc[j4 * 4 + 3] += xv * w4.w;
      }
    }
  }
}

// ---------------- fused q + kv GEMM (z<2: q 96-oc blocks; z>=2: kv 96-oc blocks) ----
__global__ __launch_bounds__(256) void k_qkv(
    const float* __restrict__ t, const float* __restrict__ qt, const float* __restrict__ kvt,
    const float* __restrict__ qb, const float* __restrict__ qe,
    const float* __restrict__ tmp, const float* __restrict__ ss,
    const float* __restrict__ kb_,
    float* __restrict__ qno, float* __restrict__ qso, float* __restrict__ kmap) {
  __shared__ float xs[32 * 66];
  const int tid = threadIdx.x;
  const int lane = tid & 63;
  const int wv = __builtin_amdgcn_readfirstlane(tid >> 6);
  const int n0 = blockIdx.x * 64;
  const int b = blockIdx.y;
  const int z = blockIdx.z;
  const int n = n0 + lane;
  float acc[24];
#pragma unroll
  for (int j = 0; j < 24; ++j) acc[j] = 0.f;

  if (z < 2) {
    const int obase = z * 96;
    const int hh = z * 4 + wv;
    const int oc0 = obase + wv * 24;
    gemm_tiles<96>(xs, tid, lane, wv, qt, 192, obase, acc,
      [&](int k0, int f) {
        int nl = f >> 5, kk = f & 31;
        return t[((size_t)b * 4096 + n0 + nl) * 192 + k0 + kk];
      },
      [&](int f) { return (f & 31) * 66 + (f >> 5); });

    float ssv = ss[n];
    float sumsq = 0.f;
#pragma unroll
    for (int d = 0; d < 24; ++d) {
      float v = acc[d] + qb[oc0 + d];
      sumsq += v * v;
    }
    float rn = 1.f / fmaxf(sqrtf(sumsq), 1e-12f);
    float sp = log1pf(__expf(tmp[hh]));
#pragma unroll
    for (int d = 0; d < 24; ++d) {
      float qv = (acc[d] + qb[oc0 + d]) * rn;
      size_t o = ((size_t)(b * 8 + hh) * 24 + d) * 4096 + n;
      qno[o] = qv;
      qso[o] = (qv + qe[hh * 24 + d]) * sp * ssv;
    }
  } else {
    const int obase = (z - 2) * 96;
    const int oc0 = obase + wv * 24;
    gemm_tiles<96>(xs, tid, lane, wv, kvt, 384, obase, acc,
      [&](int k0, int f) {
        int nl = f >> 5, kk = f & 31;
        return t[((size_t)b * 4096 + n0 + nl) * 192 + k0 + kk];
      },
      [&](int f) { return (f & 31) * 66 + (f >> 5); });

    if (oc0 < 192) {
      float sumsq = 0.f;
#pragma unroll
      for (int d = 0; d < 24; ++d) {
        float v = acc[d] + kb_[oc0 + d];
        sumsq += v * v;
      }
      float rn = 1.f / fmaxf(sqrtf(sumsq), 1e-12f);
#pragma unroll
      for (int d = 0; d < 24; ++d)
        kmap[((size_t)b * 384 + oc0 + d) * 4096 + n] = (acc[d] + kb_[oc0 + d]) * rn;
    } else {
#pragma unroll
      for (int d = 0; d < 24; ++d)
        kmap[((size_t)b * 384 + oc0 + d) * 4096 + n] = acc[d] + kb_[oc0 + d];
    }
  }
}

// ---------------- sr GEMM (48 oc/block) + exact gelu + 4x4 mean-pool ----------------
__device__ __forceinline__ float gelu_exact(float v) {
  float u = v * 0.70710678118654752f;
  float a = fabsf(u);
  float tt = 1.f / (1.f + 0.3275911f * a);
  float poly = ((((1.061405429f * tt - 1.453152027f) * tt + 1.421413741f) * tt
                 - 0.284496736f) * tt + 0.254829592f) * tt;
  float erfa = 1.f - poly * __expf(-a * a);
  float erfv = (u < 0.f) ? -erfa : erfa;
  return 0.5f * v * (1.f + erfv);
}

__global__ __launch_bounds__(256) void k_srpool(
    const float* __restrict__ t, const float* __restrict__ srt, const float* __restrict__ sb,
    float* __restrict__ pooled) {
  __shared__ float xs[32 * 66];
  const int tid = threadIdx.x;
  const int lane = tid & 63;
  const int wv = __builtin_amdgcn_readfirstlane(tid >> 6);
  const int wx = blockIdx.x & 3;
  const int obase = (blockIdx.x >> 2) * 48;
  const int ph = blockIdx.y;
  const int b = blockIdx.z;
  const int oc0 = obase + wv * 12;
  float acc[12];
#pragma unroll
  for (int j = 0; j < 12; ++j) acc[j] = 0.f;

  gemm_tiles<48>(xs, tid, lane, wv, srt, 192, obase, acc,
    [&](int k0, int f) {
      int pl = f >> 5, kk = f & 31;
      int row = (ph * 4 + (pl >> 4)) * 64 + wx * 16 + (pl & 15);
      return t[((size_t)b * 4096 + row) * 192 + k0 + kk];
    },
    [&](int f) { return (f & 31) * 66 + (f >> 5); });

#pragma unroll
  for (int j = 0; j < 12; ++j) {
    float gv = gelu_exact(acc[j] + sb[oc0 + j]);
    gv += __shfl_xor(gv, 1, 64);
    gv += __shfl_xor(gv, 2, 64);
    gv += __shfl_xor(gv, 16, 64);
    gv += __shfl_xor(gv, 32, 64);
    if ((lane & 51) == 0) {
      int cell = (lane >> 2) & 3;
      int p = ph * 16 + wx * 4 + cell;
      pooled[((size_t)b * 256 + p) * 192 + oc0 + j] = gv * (1.f / 16.f);
    }
  }
}

// ---------------- pooled kv (96 of 384 oc/block) -> kp/vp [b][h][m][24] ----------------
__global__ __launch_bounds__(256) void k_kvp(
    const float* __restrict__ pooled, const float* __restrict__ kvt, const float* __restrict__ kb_,
    float* __restrict__ kp, float* __restrict__ vp) {
  __shared__ float xs[32 * 66];
  const int tid = threadIdx.x;
  const int lane = tid & 63;
  const int wv = __builtin_amdgcn_readfirstlane(tid >> 6);
  const int r0 = blockIdx.x * 64;
  const int obase = blockIdx.y * 96;
  const int oc0 = obase + wv * 24;
  const int row = r0 + lane;
  const int b = row >> 8;
  const int m = row & 255;
  float acc[24];
#pragma unroll
  for (int j = 0; j < 24; ++j) acc[j] = 0.f;

  gemm_tiles<96>(xs, tid, lane, wv, kvt, 384, obase, acc,
    [&](int k0, int f) {
      int nl = f >> 5, kk = f & 31;
      return pooled[(size_t)(r0 + nl) * 192 + k0 + kk];
    },
    [&](int f) { return (f & 31) * 66 + (f >> 5); });

  if (oc0 < 192) {
    int hh = oc0 / 24;
    float sumsq = 0.f;
#pragma unroll
    for (int d = 0; d < 24; ++d) {
      float v = acc[d] + kb_[oc0 + d];
      sumsq += v * v;
    }
    float rn = 1.f / fmaxf(sqrtf(sumsq), 1e-12f);
#pragma unroll
    for (int d = 0; d < 24; ++d)
      kp[(((size_t)(b * 8 + hh)) * 256 + m) * 24 + d] = (acc[d] + kb_[oc0 + d]) * rn;
  } else {
    int hh = (oc0 - 192) / 24;
#pragma unroll
    for (int d = 0; d < 24; ++d)
      vp[(((size_t)(b * 8 + hh)) * 256 + m) * 24 + d] = acc[d] + kb_[oc0 + d];
  }
}

// ---------------- cpb MLP: (T,2) -> (T,8), weights staged in LDS ----------------
__global__ __launch_bounds__(256) void k_cpb(
    const float* __restrict__ coords, const float* __restrict__ c1w,
    const float* __restrict__ c1b, const float* __restrict__ c2w,
    const float* __restrict__ c2b, float* __restrict__ cpb, int T) {
  __shared__ float s1w[1024];     // [j][2]
  __shared__ float s1b[512];
  __shared__ __align__(16) float s2w[512 * 8];  // [j][h]
  const int tid = threadIdx.x;
  for (int f = tid; f < 1024; f += 256) s1w[f] = c1w[f];
  for (int f = tid; f < 512; f += 256) s1b[f] = c1b[f];
  for (int f = tid; f < 4096; f += 256) {
    int h = f >> 9, j = f & 511;
    s2w[j * 8 + h] = c2w[f];
  }
  __syncthreads();
  int i = blockIdx.x * 256 + tid;
  int ic = (i < T) ? i : (T - 1);
  float x0 = coords[2 * ic], y0 = coords[2 * ic + 1];
  float a[8];
#pragma unroll
  for (int h = 0; h < 8; ++h) a[h] = c2b[h];
#pragma unroll 4
  for (int j = 0; j < 512; ++j) {
    float hv = fmaxf(s1w[2 * j] * x0 + s1w[2 * j + 1] * y0 + s1b[j], 0.f);
    const float4* w2 = (const float4*)&s2w[j * 8];
    float4 wA = w2[0], wB = w2[1];
    a[0] += hv * wA.x; a[1] += hv * wA.y; a[2] += hv * wA.z; a[3] += hv * wA.w;
    a[4] += hv * wB.x; a[5] += hv * wB.y; a[6] += hv * wB.z; a[7] += hv * wB.w;
  }
  if (i < T) {
#pragma unroll
    for (int h = 0; h < 8; ++h) cpb[(size_t)i * 8 + h] = a[h];
  }
}

// ---------------- pool bias gather: bt[h][n][m] (bf16, m-contiguous) ----------------
__global__ __launch_bounds__(256) void k_bias(
    const int* __restrict__ rel, const float* __restrict__ cpb,
    unsigned short* __restrict__ bt) {
  int g = blockIdx.x * 256 + threadIdx.x;   // 131072 total = 4096 n * 32 chunks
  int n = g >> 5;
  int m0 = (g & 31) * 8;
  const int4* r4 = (const int4*)(rel + (size_t)n * 256 + m0);
  int4 ra = r4[0], rb = r4[1];
  int idxs[8] = {ra.x, ra.y, ra.z, ra.w, rb.x, rb.y, rb.z, rb.w};
  unsigned acc[8][4];
#pragma unroll
  for (int j = 0; j < 8; ++j) {
    const float4* c4 = (const float4*)(cpb + (size_t)idxs[j] * 8);
    float4 A = c4[0], Bv = c4[1];
    float vals[8] = {A.x, A.y, A.z, A.w, Bv.x, Bv.y, Bv.z, Bv.w};
#pragma unroll
    for (int hh = 0; hh < 8; ++hh) {
      unsigned u = f2b(vals[hh]);
      if (j & 1) acc[hh][j >> 1] |= u << 16;
      else       acc[hh][j >> 1]  = u;
    }
  }
#pragma unroll
  for (int hh = 0; hh < 8; ++hh) {
    uint4 o;
    o.x = acc[hh][0]; o.y = acc[hh][1]; o.z = acc[hh][2]; o.w = acc[hh][3];
    *(uint4*)(bt + ((size_t)hh * 4096 + n) * 256 + m0) = o;
  }
}

// ---------------- fused attention; 512 threads = 2 rows x 4 m-quarter waves ----------------
// (round-10 proven structure: kp/vp staged in LDS, bias via prefetched uint4)
__global__ __launch_bounds__(512, 4) void k_attn(
    const float* __restrict__ qs_g, const float* __restrict__ qn_g,
    const float* __restrict__ kmap, const float* __restrict__ kp, const float* __restrict__ vp,
    const unsigned short* __restrict__ bt, const float* __restrict__ rpb,
    const float* __restrict__ lt, const float* __restrict__ lb,
    float* __restrict__ ctx) {
  __shared__ __align__(16) float smem[12288];  // kl[6144] | vl[6144]; reused for reduction
  float* kl = smem;
  float* vl = smem + 6144;
  const int tid = threadIdx.x;
  const int lane = tid & 63;
  const int w = __builtin_amdgcn_readfirstlane(tid >> 6);
  const int qm = w & 3;          // m-quarter / local-tap subset
  const int rr = w >> 2;         // row within the pair
  const int row = blockIdx.x * 2 + rr;
  const int h = blockIdx.y;
  const int b = blockIdx.z;
  const int n = (row << 6) + lane;
  const float SHIFT = 15.f;

  // stage pooled k/v into LDS (loads issued now; consumed after local part)
  {
    const float4* kps = (const float4*)(kp + (size_t)(b * 8 + h) * 6144);
    const float4* vps = (const float4*)(vp + (size_t)(b * 8 + h) * 6144);
    float4* kld = (float4*)kl;
    float4* vld = (float4*)vl;
#pragma unroll
    for (int c = 0; c < 3; ++c) {
      int f = tid + c * 512;
      kld[f] = kps[f];
      vld[f] = vps[f];
    }
  }

  float qsv[24];
  {
    const float* qsb = qs_g + ((size_t)(b * 8 + h) * 24) * 4096 + n;
#pragma unroll
    for (int d = 0; d < 24; ++d) qsv[d] = qsb[(size_t)d * 4096];
  }

  // local-tap subsets: qm1 -> {0,1,2}; qm0 -> {3,4}; qm2 -> {5,6}; qm3 -> {7,8}
  const int l0 = (qm == 1) ? 0 : ((qm == 0) ? 3 : (qm * 2 + 1));
  const int lcnt = (qm == 1) ? 3 : 2;

  float wlv[3];
  {
    float qnv[24];
    const float* qnb = qn_g + ((size_t)(b * 8 + h) * 24) * 4096 + n;
#pragma unroll
    for (int d = 0; d < 24; ++d) qnv[d] = qnb[(size_t)d * 4096];
    const float* ltp = lt + h * 216;
    const float* lbp = lb + h * 9;
#pragma unroll
    for (int j = 0; j < 3; ++j) {
      float a = 0.f;
      if (j < lcnt) {
        int l = l0 + j;
#pragma unroll
        for (int d = 0; d < 24; ++d) a += qnv[d] * ltp[d * 9 + l];
        a += lbp[l];
      }
      wlv[j] = a;
    }
  }

  float ctxA[24], ctxBP[24];
#pragma unroll
  for (int d = 0; d < 24; ++d) { ctxA[d] = 0.f; ctxBP[d] = 0.f; }
  float S = 0.f;

  // local window (this wave's tap subset); row is wave-uniform
  {
    const float* kbase = kmap + ((size_t)b * 384 + h * 24) * 4096;
    const float* rpp = rpb + h * 9;
    for (int j = 0; j < lcnt; ++j) {
      const int l = l0 + j;
      const int dh = l / 3 - 1, dw = l % 3 - 1;
      const int hp = row + dh;
      if (hp < 0 || hp >= 64) continue;        // wave-uniform branch
      const int wp2 = lane + dw;
      const bool okw = (wp2 >= 0) && (wp2 < 64);
      const int nn = (hp << 6) + (okw ? wp2 : lane);  // clamped safe addr
      const float* kb = kbase + nn;
      const float* vb = kb + (size_t)192 * 4096;
      float d0 = 0, d1 = 0, d2 = 0, d3 = 0;
#pragma unroll
      for (int d = 0; d < 24; d += 4) {
        d0 += qsv[d] * kb[(size_t)d * 4096];
        d1 += qsv[d + 1] * kb[(size_t)(d + 1) * 4096];
        d2 += qsv[d + 2] * kb[(size_t)(d + 2) * 4096];
        d3 += qsv[d + 3] * kb[(size_t)(d + 3) * 4096];
      }
      float p = okw ? __expf((d0 + d1) + (d2 + d3) + rpp[l] - SHIFT) : 0.f;
      S += p;
      float wll = okw ? wlv[j] : 0.f;
#pragma unroll
      for (int d = 0; d < 24; ++d) {
        float vv = vb[(size_t)d * 4096];
        ctxA[d] += wll * vv;
        ctxBP[d] += p * vv;
      }
    }
  }

  __syncthreads();  // kp/vp staged

  // pooled keys: this wave's 64-m quarter; bias loaded as uint4 with 1-chunk prefetch
  {
    const unsigned short* bp = bt + ((size_t)h * 4096 + n) * 256 + qm * 64;
    const float* klq = kl + qm * (64 * 24);
    const float* vlq = vl + qm * (64 * 24);
    uint4 bcur = *(const uint4*)bp;
#pragma unroll 1
    for (int c = 0; c < 8; ++c) {
      uint4 bnx = bcur;
      if (c < 7) bnx = *(const uint4*)(bp + (c + 1) * 8);
#pragma unroll
      for (int j = 0; j < 8; ++j) {
        const float4* kr4 = (const float4*)&klq[(c * 8 + j) * 24];
        const float4* vr4 = (const float4*)&vlq[(c * 8 + j) * 24];
        float d0 = 0, d1 = 0, d2 = 0, d3 = 0;
#pragma unroll
        for (int q4 = 0; q4 < 6; ++q4) {
          float4 k4 = kr4[q4];
          d0 += qsv[q4 * 4 + 0] * k4.x;
          d1 += qsv[q4 * 4 + 1] * k4.y;
          d2 += qsv[q4 * 4 + 2] * k4.z;
          d3 += qsv[q4 * 4 + 3] * k4.w;
        }
        unsigned word = (j < 2) ? bcur.x : (j < 4) ? bcur.y : (j < 6) ? bcur.z : bcur.w;
        float bv = (j & 1) ? __uint_as_float(word & 0xffff0000u)
                           : __uint_as_float(word << 16);
        float p = __expf((d0 + d1) + (d2 + d3) + bv - SHIFT);
        S += p;
#pragma unroll
        for (int q4 = 0; q4 < 6; ++q4) {
          float4 v4 = vr4[q4];
          ctxBP[q4 * 4 + 0] += p * v4.x;
          ctxBP[q4 * 4 + 1] += p * v4.y;
          ctxBP[q4 * 4 + 2] += p * v4.z;
          ctxBP[q4 * 4 + 3] += p * v4.w;
        }
      }
      bcur = bnx;
    }
  }

  // cross-quarter reduction (stride 49 floats: odd -> bank-conflict-free)
  for (int src = 1; src < 4; ++src) {
    __syncthreads();
    if (qm == src) {
      float* p = smem + (size_t)(rr * 64 + lane) * 49;
      p[0] = S;
#pragma unroll
      for (int d = 0; d < 24; ++d) { p[1 + d] = ctxA[d]; p[25 + d] = ctxBP[d]; }
    }
    __syncthreads();
    if (qm == 0) {
      const float* p = smem + (size_t)(rr * 64 + lane) * 49;
      S += p[0];
#pragma unroll
      for (int d = 0; d < 24; ++d) { ctxA[d] += p[1 + d]; ctxBP[d] += p[25 + d]; }
    }
  }
  if (qm == 0) {
    const float inv = 1.f / S;
    float* cb = ctx + ((size_t)(b * 8 + h) * 24) * 4096 + n;
#pragma unroll
    for (int d = 0; d < 24; ++d)
      cb[(size_t)d * 4096] = ctxA[d] + ctxBP[d] * inv;
  }
}

// ---------------- fused proj GEMM + output LN; 512 threads = 8 waves x 24 oc ----------
__global__ __launch_bounds__(512) void k_projoln(
    const float* __restrict__ ctx, const float* __restrict__ pjt, const float* __restrict__ pb,
    const float* __restrict__ g, const float* __restrict__ be, float* __restrict__ out) {
  __shared__ float xs[32 * 66];
  __shared__ float red[2][8][64];
  const int tid = threadIdx.x;
  const int lane = tid & 63;
  const int wv = __builtin_amdgcn_readfirstlane(tid >> 6);   // 0..7
  const int n0 = blockIdx.x * 64;
  const int b = blockIdx.y;
  const int oc0 = wv * 24;
  float acc[24];
#pragma unroll
  for (int j = 0; j < 24; ++j) acc[j] = 0.f;

  float xr[4];
  auto loadx = [&](int k0) {
#pragma unroll
    for (int s = 0; s < 4; ++s) {
      int f = tid + s * 512;
      int kk = f >> 6, nl = f & 63;
      xr[s] = ctx[((size_t)b * 192 + k0 + kk) * 4096 + n0 + nl];
    }
  };
  loadx(0);
  for (int kt = 0; kt < 6; ++kt) {
    __syncthreads();
#pragma unroll
    for (int s = 0; s < 4; ++s) {
      int f = tid + s * 512;
      xs[(f >> 6) * 66 + (f & 63)] = xr[s];
    }
    __syncthreads();
    if (kt < 5) loadx((kt + 1) * 32);
    const float* wbase = pjt + (size_t)kt * 32 * 192 + oc0;
#pragma unroll 4
    for (int kk = 0; kk < 32; ++kk) {
      float xv = xs[kk * 66 + lane];
      const float4* wrow = (const float4*)(wbase + (size_t)kk * 192);
#pragma unroll
      for (int j4 = 0; j4 < 6; ++j4) {
        float4 w4 = wrow[j4];
        acc[j4 * 4 + 0] += xv * w4.x;
        acc[j4 * 4 + 1] += xv * w4.y;
        acc[j4 * 4 + 2] += xv * w4.z;
        acc[j4 * 4 + 3] += xv * w4.w;
      }
    }
  }

  // bias + LN partials
  float v[24];
  float s = 0.f, sq = 0.f;
#pragma unroll
  for (int d = 0; d < 24; ++d) {
    v[d] = acc[d] + pb[oc0 + d];
    s += v[d];
    sq += v[d] * v[d];
  }
  red[0][wv][lane] = s;
  red[1][wv][lane] = sq;
  __syncthreads();
  float st = 0.f, sqt = 0.f;
#pragma unroll
  for (int k = 0; k < 8; ++k) {
    st += red[0][k][lane];
    sqt += red[1][k][lane];
  }
  float mean = st * (1.f / 192.f);
  float var = sqt * (1.f / 192.f) - mean * mean;
  float rstd = rsqrtf(var + 1e-5f);
#pragma unroll
  for (int d = 0; d < 24; ++d) {
    int o = oc0 + d;
    out[((size_t)b * 192 + o) * 4096 + n0 + lane] = (v[d] - mean) * rstd * g[o] + be[o];
  }
}

// ---------------- host launcher ----------------
extern "C" void kernel_launch(void* const* d_in, const int* in_sizes, int n_in,
                              void* d_out, int out_size, void* d_ws, size_t ws_size,
                              hipStream_t stream) {
  float* w = (float*)d_ws;

  const float* x      = (const float*)d_in[0];
  const float* pe_w   = (const float*)d_in[1];
  const float* pe_b   = (const float*)d_in[2];
  const float* peln_g = (const float*)d_in[3];
  const float* peln_b = (const float*)d_in[4];
  const float* q_w    = (const float*)d_in[5];
  const float* q_b    = (const float*)d_in[6];
  const float* kv_w   = (const float*)d_in[7];
  const float* kv_b   = (const float*)d_in[8];
  const float* sr_w   = (const float*)d_in[9];
  const float* sr_b   = (const float*)d_in[10];
  const float* norm_g = (const float*)d_in[11];
  const float* norm_b = (const float*)d_in[12];
  const float* cpb1w  = (const float*)d_in[13];
  const float* cpb1b  = (const float*)d_in[14];
  const float* cpb2w  = (const float*)d_in[15];
  const float* cpb2b  = (const float*)d_in[16];
  const float* rpb    = (const float*)d_in[17];
  const float* lt     = (const float*)d_in[18];
  const float* lb     = (const float*)d_in[19];
  const float* qe     = (const float*)d_in[20];
  const float* temp   = (const float*)d_in[21];
  const float* proj_w = (const float*)d_in[22];
  const float* proj_b = (const float*)d_in[23];
  const float* oln_g  = (const float*)d_in[24];
  const float* oln_b  = (const float*)d_in[25];
  const int*   rel    = (const int*)d_in[26];
  const float* coords = (const float*)d_in[27];
  const float* ss     = (const float*)d_in[28];

  dim3 blk(256);
  // all four weight transposes in one launch
  k_wt_all<<<dim3(1872), blk, 0, stream>>>(pe_w, q_w, kv_w, sr_w, w);

  // split-K conv: z = 4 oc-blocks x 3 ic-thirds; partials -> T, KMAP, KMAP+3145728
  k_conv<<<dim3(16, 4, 12), blk, 0, stream>>>(x, w + OFF_WTC, w + OFF_T,
      w + OFF_KMAP, w + OFF_KMAP + 3145728);
  // merge partials + conv bias + LN
  k_ln_rows<<<dim3(4096), blk, 0, stream>>>(w + OFF_T, w + OFF_KMAP,
      w + OFF_KMAP + 3145728, pe_b, peln_g, peln_b, 16384);
  // fused q + kv GEMM (z 0-1: q heads 0-7; z 2-5: kv 384 oc)
  k_qkv<<<dim3(64, 4, 6), blk, 0, stream>>>(w + OFF_T, w + OFF_QT, w + OFF_KVT,
      q_b, qe, temp, ss, kv_b, w + OFF_QN, w + OFF_QS, w + OFF_KMAP);
  k_srpool<<<dim3(16, 16, 4), blk, 0, stream>>>(w + OFF_T, w + OFF_SRT, sr_b, w + OFF_POOL);
  k_ln_rows<<<dim3(256), blk, 0, stream>>>(w + OFF_POOL, nullptr, nullptr, nullptr,
      norm_g, norm_b, 1024);
  k_kvp<<<dim3(16, 4), blk, 0, stream>>>(w + OFF_POOL, w + OFF_KVT, kv_b,
      w + OFF_KP, w + OFF_VP);
  int T = in_sizes[27] / 2;
  k_cpb<<<dim3((T + 255) / 256), blk, 0, stream>>>(coords, cpb1w, cpb1b, cpb2w, cpb2b,
      w + OFF_CPB, T);
  k_bias<<<dim3(512), blk, 0, stream>>>(rel, w + OFF_CPB,
      (unsigned short*)(w + OFF_BIAS));
  k_attn<<<dim3(32, 8, 4), dim3(512), 0, stream>>>(w + OFF_QS, w + OFF_QN, w + OFF_KMAP,
      w + OFF_KP, w + OFF_VP, (const unsigned short*)(w + OFF_BIAS), rpb, lt, lb,
      w + OFF_CTX);
  k_wt_gen<<<dim3(144), blk, 0, stream>>>(proj_w, w + OFF_PJT, 192, 192);
  // fused proj GEMM + output LN -> d_out (no pout round-trip)
  k_projoln<<<dim3(64, 4), dim3(512), 0, stream>>>(w + OFF_CTX, w + OFF_PJT, proj_b,
      oln_g, oln_b, (float*)d_out);
}